// Round 2
// baseline (76.839 us; speedup 1.0000x reference)
//
#include <hip/hip_runtime.h>

// Depth-4 path signature, B=128, L=128, C=12, fp32.
// Round 7: attack the two residuals of the ~30us main loop:
//   (1) LDS-pipe oversubscription: the 12 broadcast wq reads/iter were
//       issued by EVERY wave (7 waves/CU) -> per-CU LDS pipe ~1300 cyc/iter.
//       Fix: k-quad per thread (thread owns i, j, and FOUR k's) halves the
//       wave count (4 waves/block of 256 thr) -> halves broadcast traffic,
//       and amortizes the Chen chain (66 VALU per step for 48 level-4 FMAs
//       vs 2x38 for 2x24 with k-pairs).
//   (2) Exposed ds_read latency at ~2 waves/SIMD: loads were consumed in
//       the same iteration they were issued. Fix: explicit register
//       double-buffer (wqA/trA vs wqB/trB), sq-loop unrolled x2, prefetch
//       iteration n+1 during iteration n's ~530 issue cycles.
// Grid 256 blocks x 256 threads (216 active = 6(i) * 12(j) * 3(k-quads)),
// 1 block/CU, 1 wave/SIMD, ~215 VGPR (no spill, 512 physical available).
// Arithmetic per output element is bit-identical to R6.

#define NC    12
#define NPTS  128
#define OUT_PER_B 22620      // 12 + 144 + 1728 + 20736
#define BT 256               // 216 active
#define PADQ 33              // float4 row stride in transposed LDS table

__global__ __launch_bounds__(BT)
void sig_kernel(const float* __restrict__ path, float* __restrict__ out) {
    const int bid = blockIdx.x;
    const int b  = bid >> 1;
    const int ih = bid & 1;
    const int t  = threadIdx.x;

    __shared__ __align__(16) float  P[NPTS * NC];     // 6144 B staged path
    __shared__ __align__(16) float  W[NPTS * NC];     // 6144 B row-major [s][c]
    __shared__ __align__(16) float4 DT4[NC * PADQ];   // 6336 B transposed [c][sq]

    // ---- stage path, coalesced (384 float4 = 6 KB) ----
    {
        const float4* pb4 = (const float4*)(path + (size_t)b * (NPTS * NC));
        ((float4*)P)[t] = pb4[t];
        if (t < 128) ((float4*)P)[t + 256] = pb4[t + 256];
    }
    __syncthreads();

    // ---- increments into both LDS layouts (one-time) ----
    #pragma unroll
    for (int pass = 0; pass < 2; ++pass) {
        const int idx = t + pass * 256;
        if (idx < 384) {
            const int c  = idx >> 5;     // 0..11
            const int sq = idx & 31;     // 0..31
            float d[4];
            #pragma unroll
            for (int e = 0; e < 4; ++e) {
                const int s = 4 * sq + e;
                d[e] = (s < NPTS - 1) ? (P[(s + 1) * NC + c] - P[s * NC + c]) : 0.f;
                W[s * NC + c] = d[e];
            }
            DT4[c * PADQ + sq] = make_float4(d[0], d[1], d[2], d[3]);
        }
    }
    __syncthreads();

    // ---- index map: thread owns (i, j, k-quad); pads duplicate work ----
    const int ta  = (t < 216) ? t : (t - 216);
    const int il  = ta / 36;
    const int rem = ta - il * 36;
    const int j   = rem / 3;
    const int kq  = rem - j * 3;
    const int i   = ih * 6 + il;
    const int k0  = kq * 4;

    float acc[4][12];
    #pragma unroll
    for (int m = 0; m < 4; ++m)
        #pragma unroll
        for (int l = 0; l < 12; ++l) acc[m][l] = 0.f;
    float s1 = 0.f, s2 = 0.f;
    float s3[4] = {0.f, 0.f, 0.f, 0.f};

    const float4* wt   = (const float4*)W;        // 12 float4 per 4-step group
    const float4* dti  = &DT4[i * PADQ];
    const float4* dtj  = &DT4[j * PADQ];
    const float4* dtk0 = &DT4[(k0 + 0) * PADQ];
    const float4* dtk1 = &DT4[(k0 + 1) * PADQ];
    const float4* dtk2 = &DT4[(k0 + 2) * PADQ];
    const float4* dtk3 = &DT4[(k0 + 3) * PADQ];

    float4 wqA[12], wqB[12];   // broadcast buffers (block-uniform addresses)
    float4 trA[6],  trB[6];    // per-thread transposed buffers

#define LOADBUF(WQ, TR, S) do {                                   \
        _Pragma("unroll")                                         \
        for (int q = 0; q < 12; ++q) WQ[q] = wt[(S) * 12 + q];    \
        TR[0] = dti[S];  TR[1] = dtj[S];                          \
        TR[2] = dtk0[S]; TR[3] = dtk1[S];                         \
        TR[4] = dtk2[S]; TR[5] = dtk3[S];                         \
    } while (0)

#define COMPUTE(WQ, TR) do {                                      \
        _Pragma("unroll")                                         \
        for (int u = 0; u < 4; ++u) {                             \
            const float di  = (&TR[0].x)[u];                      \
            const float dj  = (&TR[1].x)[u];                      \
            const float dk0_ = (&TR[2].x)[u];                     \
            const float dk1_ = (&TR[3].x)[u];                     \
            const float dk2_ = (&TR[4].x)[u];                     \
            const float dk3_ = (&TR[5].x)[u];                     \
            float A4 = (s1 + 0.25f * di) * (1.f / 3.f);           \
            float B4 = (s2 + dj * A4) * 0.5f;                     \
            float C3_0 = s3[0] + dk0_ * B4;                       \
            float C3_1 = s3[1] + dk1_ * B4;                       \
            float C3_2 = s3[2] + dk2_ * B4;                       \
            float C3_3 = s3[3] + dk3_ * B4;                       \
            _Pragma("unroll")                                     \
            for (int l = 0; l < 12; ++l) {                        \
                const float wl = (&WQ[3 * u + (l >> 2)].x)[l & 3];\
                acc[0][l] += C3_0 * wl;                           \
                acc[1][l] += C3_1 * wl;                           \
                acc[2][l] += C3_2 * wl;                           \
                acc[3][l] += C3_3 * wl;                           \
            }                                                     \
            float A3 = (s1 + di * (1.f / 3.f)) * 0.5f;            \
            float C2 = s2 + dj * A3;                              \
            s3[0] += dk0_ * C2;                                   \
            s3[1] += dk1_ * C2;                                   \
            s3[2] += dk2_ * C2;                                   \
            s3[3] += dk3_ * C2;                                   \
            s2 += dj * (s1 + 0.5f * di);                          \
            s1 += di;                                             \
        }                                                         \
    } while (0)

    // ---- software-pipelined main loop: prefetch n+1 while computing n ----
    LOADBUF(wqA, trA, 0);
    for (int sq = 0; sq < 32; sq += 2) {
        LOADBUF(wqB, trB, sq + 1);
        COMPUTE(wqA, trA);
        if (sq + 2 < 32) LOADBUF(wqA, trA, sq + 2);
        COMPUTE(wqB, trB);
    }

#undef LOADBUF
#undef COMPUTE

    if (t < 216) {
        float* ob = out + (size_t)b * OUT_PER_B;
        if (j == 0 && kq == 0) ob[i] = s1;                 // level 1
        if (kq == 0) ob[12 + i * 12 + j] = s2;             // level 2
        const int ijk = (i * 12 + j) * 12 + k0;
        *(float4*)(ob + 156 + ijk) =                       // level 3 (quad)
            make_float4(s3[0], s3[1], s3[2], s3[3]);
        float4* o4 = (float4*)(ob + 1884 + (size_t)ijk * 12);  // level 4, 192B
        #pragma unroll
        for (int m = 0; m < 4; ++m) {
            o4[m * 3 + 0] = make_float4(acc[m][0], acc[m][1], acc[m][2],  acc[m][3]);
            o4[m * 3 + 1] = make_float4(acc[m][4], acc[m][5], acc[m][6],  acc[m][7]);
            o4[m * 3 + 2] = make_float4(acc[m][8], acc[m][9], acc[m][10], acc[m][11]);
        }
    }
}

extern "C" void kernel_launch(void* const* d_in, const int* in_sizes, int n_in,
                              void* d_out, int out_size, void* d_ws, size_t ws_size,
                              hipStream_t stream) {
    const float* path = (const float*)d_in[0];
    float* out = (float*)d_out;
    const int nbatch = in_sizes[0] / (NPTS * NC);   // = 128

    sig_kernel<<<nbatch * 2, BT, 0, stream>>>(path, out);
}